// Round 1
// baseline (13777.548 us; speedup 1.0000x reference)
//
#include <hip/hip_runtime.h>
#include <math.h>

#define TT   2048
#define CC   768
#define NH   12
#define DH   64
#define NL   6
#define VV   50257
#define BTOT 4096   // B*T

typedef unsigned short u16;

__device__ __forceinline__ float bf2f(u16 u) {
  return __uint_as_float(((unsigned int)u) << 16);
}
__device__ __forceinline__ u16 f2bf(float f) {
  unsigned int x = __float_as_uint(f);
  return (u16)((x + 0x7FFFu + ((x >> 16) & 1u)) >> 16);  // RNE
}
// load external float tensor element (bf16 or fp32 per runtime flag)
__device__ __forceinline__ float ldf(const void* p, size_t idx, bool isbf) {
  return isbf ? bf2f(((const u16*)p)[idx]) : ((const float*)p)[idx];
}

// ---------------- dtype detector ----------------
// If wte is bf16, even-indexed ushorts are N(0,0.02) values -> |v| in (1e-6,1).
// If wte is fp32, even-indexed ushorts are fp32 mantissa low bits -> mostly insane.
__global__ void detect_kernel(const void* __restrict__ wte, int* __restrict__ flag) {
  const u16* p = (const u16*)wte;
  int t = threadIdx.x;
  int sane = 0;
  for (int u = 0; u < 4; ++u) {
    float f = fabsf(bf2f(p[(t * 4 + u) * 2]));
    if (f > 1e-6f && f < 1.0f) sane++;
  }
  __shared__ int cnt;
  if (t == 0) cnt = 0;
  __syncthreads();
  atomicAdd(&cnt, sane);
  __syncthreads();
  if (t == 0) *flag = (cnt > 512) ? 1 : 0;   // of 1024 samples
}

// ---------------- embedding: h = wte[x] + wpe[t] ----------------
__global__ __launch_bounds__(256) void embed_kernel(
    const int* __restrict__ x, const void* __restrict__ wte,
    const void* __restrict__ wpe, float* __restrict__ h,
    const int* __restrict__ flagp) {
  bool isbf = (*flagp != 0);
  int i = blockIdx.x * 256 + threadIdx.x;
  if (i >= BTOT * CC) return;
  int bt = i / CC, c = i - bt * CC;
  int tpos = bt & (TT - 1);
  size_t wi = (size_t)x[bt] * CC + c;
  size_t pi = (size_t)tpos * CC + c;
  h[i] = ldf(wte, wi, isbf) + ldf(wpe, pi, isbf);
}

// ---------------- layernorm (one block per row, C=768 = 3 floats/thread) ----------------
__global__ __launch_bounds__(256) void ln_kernel(
    const float* __restrict__ x, const void* __restrict__ wv,
    const void* __restrict__ bv, size_t loff, float* __restrict__ out,
    const int* __restrict__ flagp) {
  bool isbf = (*flagp != 0);
  int row = blockIdx.x;
  int t = threadIdx.x;
  const float* xr = x + (size_t)row * CC;
  float v0 = xr[t], v1 = xr[t + 256], v2 = xr[t + 512];
  float s = v0 + v1 + v2;
  float q = v0 * v0 + v1 * v1 + v2 * v2;
  #pragma unroll
  for (int o = 32; o > 0; o >>= 1) { s += __shfl_down(s, o); q += __shfl_down(q, o); }
  __shared__ float rs[4], rq[4], stat[2];
  int wid = t >> 6, lane = t & 63;
  if (lane == 0) { rs[wid] = s; rq[wid] = q; }
  __syncthreads();
  if (t == 0) {
    float S = rs[0] + rs[1] + rs[2] + rs[3];
    float Q = rq[0] + rq[1] + rq[2] + rq[3];
    float m = S * (1.0f / CC);
    stat[0] = m;
    stat[1] = rsqrtf(Q * (1.0f / CC) - m * m + 1e-5f);
  }
  __syncthreads();
  float m = stat[0], r = stat[1];
  float* orow = out + (size_t)row * CC;
  orow[t]       = (v0 - m) * r * ldf(wv, loff + t, isbf)       + ldf(bv, loff + t, isbf);
  orow[t + 256] = (v1 - m) * r * ldf(wv, loff + t + 256, isbf) + ldf(bv, loff + t + 256, isbf);
  orow[t + 512] = (v2 - m) * r * ldf(wv, loff + t + 512, isbf) + ldf(bv, loff + t + 512, isbf);
}

// ---------------- GEMM: C[m,n] = op( sum_k A[m,k]*B[n,k] + bias[n] ) ----------------
// A fp32 (internal activations). B/bias external (flag dtype).
// 128x128 block tile, BK=16, 256 threads, 8x8 microtile.
// OUTFLAG: store to d_out (element offset +1) in flag dtype (LM head).
template<int RELU, int ADDDST, int BIAS, int OUTFLAG>
__global__ __launch_bounds__(256) void gemm_nt(
    const float* __restrict__ A, const void* __restrict__ Bv, size_t Boff,
    const void* __restrict__ biasv, size_t biasoff, void* __restrict__ Cv,
    int N, int K, const int* __restrict__ flagp) {
  bool isbf = (*flagp != 0);
  __shared__ __align__(16) float As[16][132];
  __shared__ __align__(16) float Bs[16][132];
  int t = threadIdx.x;
  int tr = t >> 4, tc = t & 15;
  int bm = blockIdx.y << 7, bn = blockIdx.x << 7;
  float acc[8][8];
  #pragma unroll
  for (int i = 0; i < 8; ++i)
    #pragma unroll
    for (int j = 0; j < 8; ++j) acc[i][j] = 0.0f;

  int r0  = t >> 2;          // 0..63
  int kc0 = (t & 3) << 2;    // 0,4,8,12
  const float* Bf = (const float*)Bv;
  const u16*   Bh = (const u16*)Bv;

  for (int k0 = 0; k0 < K; k0 += 16) {
    __syncthreads();
    #pragma unroll
    for (int u = 0; u < 2; ++u) {
      int row = r0 + (u << 6);
      float4 av = *(const float4*)(A + (size_t)(bm + row) * K + (k0 + kc0));
      As[kc0 + 0][row] = av.x; As[kc0 + 1][row] = av.y;
      As[kc0 + 2][row] = av.z; As[kc0 + 3][row] = av.w;
      int n = bn + row;
      float b0 = 0.f, b1 = 0.f, b2 = 0.f, b3 = 0.f;
      if (n < N) {
        size_t off = Boff + (size_t)n * K + (k0 + kc0);
        if (isbf) {
          ushort4 raw = *(const ushort4*)(Bh + off);
          b0 = bf2f(raw.x); b1 = bf2f(raw.y); b2 = bf2f(raw.z); b3 = bf2f(raw.w);
        } else {
          float4 bv4 = *(const float4*)(Bf + off);
          b0 = bv4.x; b1 = bv4.y; b2 = bv4.z; b3 = bv4.w;
        }
      }
      Bs[kc0 + 0][row] = b0; Bs[kc0 + 1][row] = b1;
      Bs[kc0 + 2][row] = b2; Bs[kc0 + 3][row] = b3;
    }
    __syncthreads();
    #pragma unroll
    for (int kk = 0; kk < 16; ++kk) {
      float4 a0  = *(const float4*)&As[kk][tr << 2];
      float4 a1  = *(const float4*)&As[kk][64 + (tr << 2)];
      float4 bq0 = *(const float4*)&Bs[kk][tc << 2];
      float4 bq1 = *(const float4*)&Bs[kk][64 + (tc << 2)];
      float a[8]  = {a0.x, a0.y, a0.z, a0.w, a1.x, a1.y, a1.z, a1.w};
      float bb[8] = {bq0.x, bq0.y, bq0.z, bq0.w, bq1.x, bq1.y, bq1.z, bq1.w};
      #pragma unroll
      for (int i = 0; i < 8; ++i)
        #pragma unroll
        for (int j = 0; j < 8; ++j)
          acc[i][j] = fmaf(a[i], bb[j], acc[i][j]);
    }
  }
  #pragma unroll
  for (int i = 0; i < 8; ++i) {
    int ri = bm + ((i < 4) ? (tr << 2) + i : 64 + (tr << 2) + (i - 4));
    #pragma unroll
    for (int j = 0; j < 8; ++j) {
      int cj = bn + ((j < 4) ? (tc << 2) + j : 64 + (tc << 2) + (j - 4));
      if (cj < N) {
        float v = acc[i][j];
        if (BIAS) v += ldf(biasv, biasoff + cj, isbf);
        if (RELU) v = fmaxf(v, 0.0f);
        size_t idx = (size_t)ri * N + cj;
        if (OUTFLAG) {
          if (isbf) ((u16*)Cv)[idx + 1] = f2bf(v);
          else      ((float*)Cv)[idx + 1] = v;
        } else {
          float* Cf = (float*)Cv;
          if (ADDDST) v += Cf[idx];
          Cf[idx] = v;
        }
      }
    }
  }
}

// ---------------- causal attention (flash-style), h += softmax(QK^T)V ----------------
// Q tile = 32 rows; K/V tiles = 64 rows. qkv is [BTOT][3*CC] fp32.
// thread t: tr=t>>4 (0..15), tc=t&15. Rows {tr, tr+16}; cols {tc+16j, j=0..3}.
__global__ __launch_bounds__(256) void attn_kernel(
    const float* __restrict__ qkv, float* __restrict__ h) {
  __shared__ __align__(16) float Qs[32][68];
  __shared__ __align__(16) float Ks[64][68];
  __shared__ __align__(16) float Vt[64][68];   // transposed: Vt[d][j]
  __shared__ __align__(16) float Ps[32][68];
  int t = threadIdx.x;
  int tr = t >> 4, tc = t & 15;
  int qt = blockIdx.x;            // 0..63
  int bh = blockIdx.y;
  int b = bh / NH, hh = bh - b * NH;
  const float scale = 0.125f;     // 1/sqrt(64)
  int qi0 = qt * 32;

  {  // stage Q (scaled): thread loads 8 floats of one row
    int row = t >> 3, c0 = (t & 7) << 3;
    const float* src = qkv + (size_t)(b * TT + qi0 + row) * (3 * CC) + hh * DH + c0;
    float4 a = *(const float4*)src;
    float4 bq = *(const float4*)(src + 4);
    Qs[row][c0 + 0] = a.x * scale;  Qs[row][c0 + 1] = a.y * scale;
    Qs[row][c0 + 2] = a.z * scale;  Qs[row][c0 + 3] = a.w * scale;
    Qs[row][c0 + 4] = bq.x * scale; Qs[row][c0 + 5] = bq.y * scale;
    Qs[row][c0 + 6] = bq.z * scale; Qs[row][c0 + 7] = bq.w * scale;
  }

  float m_i[2] = {-1e30f, -1e30f};
  float l_i[2] = {0.f, 0.f};
  float O[2][4] = {{0.f, 0.f, 0.f, 0.f}, {0.f, 0.f, 0.f, 0.f}};
  int st_max = (qi0 + 31) >> 6;
  int krow = t >> 2, kc0 = (t & 3) << 4;

  for (int st = 0; st <= st_max; ++st) {
    __syncthreads();
    {  // stage K (row-major) and V (transposed)
      const float* ksrc = qkv + (size_t)(b * TT + st * 64 + krow) * (3 * CC) + CC + hh * DH + kc0;
      #pragma unroll
      for (int u = 0; u < 4; ++u) {
        float4 v = *(const float4*)(ksrc + 4 * u);
        Ks[krow][kc0 + 4 * u + 0] = v.x; Ks[krow][kc0 + 4 * u + 1] = v.y;
        Ks[krow][kc0 + 4 * u + 2] = v.z; Ks[krow][kc0 + 4 * u + 3] = v.w;
      }
      const float* vsrc = ksrc + CC;
      #pragma unroll
      for (int u = 0; u < 4; ++u) {
        float4 v = *(const float4*)(vsrc + 4 * u);
        Vt[kc0 + 4 * u + 0][krow] = v.x; Vt[kc0 + 4 * u + 1][krow] = v.y;
        Vt[kc0 + 4 * u + 2][krow] = v.z; Vt[kc0 + 4 * u + 3][krow] = v.w;
      }
    }
    __syncthreads();

    float S[2][4] = {{0.f, 0.f, 0.f, 0.f}, {0.f, 0.f, 0.f, 0.f}};
    #pragma unroll 4
    for (int d0 = 0; d0 < 64; d0 += 4) {
      float4 q0 = *(const float4*)&Qs[tr][d0];
      float4 q1 = *(const float4*)&Qs[tr + 16][d0];
      float4 k0 = *(const float4*)&Ks[tc][d0];
      float4 k1 = *(const float4*)&Ks[tc + 16][d0];
      float4 k2 = *(const float4*)&Ks[tc + 32][d0];
      float4 k3 = *(const float4*)&Ks[tc + 48][d0];
      S[0][0] += q0.x*k0.x + q0.y*k0.y + q0.z*k0.z + q0.w*k0.w;
      S[0][1] += q0.x*k1.x + q0.y*k1.y + q0.z*k1.z + q0.w*k1.w;
      S[0][2] += q0.x*k2.x + q0.y*k2.y + q0.z*k2.z + q0.w*k2.w;
      S[0][3] += q0.x*k3.x + q0.y*k3.y + q0.z*k3.z + q0.w*k3.w;
      S[1][0] += q1.x*k0.x + q1.y*k0.y + q1.z*k0.z + q1.w*k0.w;
      S[1][1] += q1.x*k1.x + q1.y*k1.y + q1.z*k1.z + q1.w*k1.w;
      S[1][2] += q1.x*k2.x + q1.y*k2.y + q1.z*k2.z + q1.w*k2.w;
      S[1][3] += q1.x*k3.x + q1.y*k3.y + q1.z*k3.z + q1.w*k3.w;
    }
    if (st == st_max) {  // causal mask only ever needed on the last tile
      #pragma unroll
      for (int i2 = 0; i2 < 2; ++i2) {
        int qi = qi0 + tr + 16 * i2;
        #pragma unroll
        for (int j = 0; j < 4; ++j) {
          int kj = st * 64 + tc + 16 * j;
          if (kj > qi) S[i2][j] = -1e30f;
        }
      }
    }
    // online softmax update (rows live in 16-lane groups: same tr, tc=0..15)
    #pragma unroll
    for (int i2 = 0; i2 < 2; ++i2) {
      float mx = fmaxf(fmaxf(S[i2][0], S[i2][1]), fmaxf(S[i2][2], S[i2][3]));
      #pragma unroll
      for (int o = 1; o < 16; o <<= 1) mx = fmaxf(mx, __shfl_xor(mx, o));
      float mnew = fmaxf(m_i[i2], mx);
      float alpha = __expf(m_i[i2] - mnew);
      float rsum = 0.f;
      #pragma unroll
      for (int j = 0; j < 4; ++j) {
        float p = __expf(S[i2][j] - mnew);
        Ps[tr + 16 * i2][tc + 16 * j] = p;
        rsum += p;
      }
      #pragma unroll
      for (int o = 1; o < 16; o <<= 1) rsum += __shfl_xor(rsum, o);
      l_i[i2] = l_i[i2] * alpha + rsum;
      m_i[i2] = mnew;
      #pragma unroll
      for (int d = 0; d < 4; ++d) O[i2][d] *= alpha;
    }
    __syncthreads();
    // O += P V
    #pragma unroll 4
    for (int j0 = 0; j0 < 64; j0 += 4) {
      float4 p0 = *(const float4*)&Ps[tr][j0];
      float4 p1 = *(const float4*)&Ps[tr + 16][j0];
      float4 v0 = *(const float4*)&Vt[tc][j0];
      float4 v1 = *(const float4*)&Vt[tc + 16][j0];
      float4 v2 = *(const float4*)&Vt[tc + 32][j0];
      float4 v3 = *(const float4*)&Vt[tc + 48][j0];
      O[0][0] += p0.x*v0.x + p0.y*v0.y + p0.z*v0.z + p0.w*v0.w;
      O[0][1] += p0.x*v1.x + p0.y*v1.y + p0.z*v1.z + p0.w*v1.w;
      O[0][2] += p0.x*v2.x + p0.y*v2.y + p0.z*v2.z + p0.w*v2.w;
      O[0][3] += p0.x*v3.x + p0.y*v3.y + p0.z*v3.z + p0.w*v3.w;
      O[1][0] += p1.x*v0.x + p1.y*v0.y + p1.z*v0.z + p1.w*v0.w;
      O[1][1] += p1.x*v1.x + p1.y*v1.y + p1.z*v1.z + p1.w*v1.w;
      O[1][2] += p1.x*v2.x + p1.y*v2.y + p1.z*v2.z + p1.w*v2.w;
      O[1][3] += p1.x*v3.x + p1.y*v3.y + p1.z*v3.z + p1.w*v3.w;
    }
  }
  #pragma unroll
  for (int i2 = 0; i2 < 2; ++i2) {
    float inv = 1.0f / l_i[i2];
    float* hp = h + (size_t)(b * TT + qi0 + tr + 16 * i2) * CC + hh * DH;
    #pragma unroll
    for (int dd = 0; dd < 4; ++dd) {
      int c = tc + 16 * dd;
      hp[c] += O[i2][dd] * inv;
    }
  }
}

// ---------------- loss: per-row lse - logit[target], then mean ----------------
__global__ __launch_bounds__(256) void loss_row_kernel(
    const void* __restrict__ outbuf, const int* __restrict__ target,
    float* __restrict__ rowloss, const int* __restrict__ flagp) {
  bool isbf = (*flagp != 0);
  int row = blockIdx.x;
  int t = threadIdx.x;
  size_t base = 1 + (size_t)row * VV;
  float mx = -1e30f;
  for (int i = t; i < VV; i += 256) mx = fmaxf(mx, ldf(outbuf, base + i, isbf));
  #pragma unroll
  for (int o = 32; o > 0; o >>= 1) mx = fmaxf(mx, __shfl_down(mx, o));
  __shared__ float rm[4], MX[1];
  int wid = t >> 6, lane = t & 63;
  if (lane == 0) rm[wid] = mx;
  __syncthreads();
  if (t == 0) MX[0] = fmaxf(fmaxf(rm[0], rm[1]), fmaxf(rm[2], rm[3]));
  __syncthreads();
  float m = MX[0];
  float s = 0.f;
  for (int i = t; i < VV; i += 256) s += __expf(ldf(outbuf, base + i, isbf) - m);
  #pragma unroll
  for (int o = 32; o > 0; o >>= 1) s += __shfl_down(s, o);
  __shared__ float rsum[4];
  if (lane == 0) rsum[wid] = s;
  __syncthreads();
  if (t == 0) {
    float S = rsum[0] + rsum[1] + rsum[2] + rsum[3];
    rowloss[row] = m + logf(S) - ldf(outbuf, base + target[row], isbf);
  }
}

__global__ __launch_bounds__(256) void loss_final(
    const float* __restrict__ rowloss, void* __restrict__ out,
    const int* __restrict__ flagp) {
  bool isbf = (*flagp != 0);
  int t = threadIdx.x;
  float s = 0.f;
  for (int i = t; i < BTOT; i += 256) s += rowloss[i];
  #pragma unroll
  for (int o = 32; o > 0; o >>= 1) s += __shfl_down(s, o);
  __shared__ float r[4];
  int wid = t >> 6, lane = t & 63;
  if (lane == 0) r[wid] = s;
  __syncthreads();
  if (t == 0) {
    float v = (r[0] + r[1] + r[2] + r[3]) * (1.0f / BTOT);
    if (isbf) ((u16*)out)[0] = f2bf(v);
    else      ((float*)out)[0] = v;
  }
}

extern "C" void kernel_launch(void* const* d_in, const int* in_sizes, int n_in,
                              void* d_out, int out_size, void* d_ws, size_t ws_size,
                              hipStream_t stream) {
  (void)in_sizes; (void)n_in; (void)out_size; (void)ws_size;
  const int*  x      = (const int*)d_in[0];
  const int*  target = (const int*)d_in[1];
  const void* wte    = d_in[2];
  const void* wpe    = d_in[3];
  const void* ln1w   = d_in[4];
  const void* ln1b   = d_in[5];
  const void* attnw  = d_in[6];
  const void* attnb  = d_in[7];
  const void* ln2w   = d_in[8];
  const void* ln2b   = d_in[9];
  const void* ff1w   = d_in[10];
  const void* ff1b   = d_in[11];
  const void* ff2w   = d_in[12];
  const void* ff2b   = d_in[13];
  const void* lmw    = d_in[14];

  float* ws  = (float*)d_ws;
  float* h   = ws;                                  // BTOT*CC
  float* xn  = h + (size_t)BTOT * CC;               // BTOT*CC
  float* big = xn + (size_t)BTOT * CC;              // BTOT*4*CC (qkv / ffn-hidden union)
  float* rowloss = big + (size_t)BTOT * 4 * CC;     // BTOT
  int*   flag = (int*)(rowloss + BTOT);

  detect_kernel<<<1, 256, 0, stream>>>(wte, flag);
  embed_kernel<<<dim3((BTOT * CC + 255) / 256), 256, 0, stream>>>(x, wte, wpe, h, flag);

  for (int l = 0; l < NL; ++l) {
    ln_kernel<<<BTOT, 256, 0, stream>>>(h, ln1w, ln1b, (size_t)l * CC, xn, flag);
    gemm_nt<0, 0, 1, 0><<<dim3(3 * CC / 128, BTOT / 128), 256, 0, stream>>>(
        xn, attnw, (size_t)l * 3 * CC * CC, attnb, (size_t)l * 3 * CC,
        big, 3 * CC, CC, flag);
    attn_kernel<<<dim3(TT / 32, 2 * NH), 256, 0, stream>>>(big, h);
    ln_kernel<<<BTOT, 256, 0, stream>>>(h, ln2w, ln2b, (size_t)l * CC, xn, flag);
    gemm_nt<1, 0, 1, 0><<<dim3(4 * CC / 128, BTOT / 128), 256, 0, stream>>>(
        xn, ff1w, (size_t)l * 4 * CC * CC, ff1b, (size_t)l * 4 * CC,
        big, 4 * CC, CC, flag);
    gemm_nt<0, 1, 1, 0><<<dim3(CC / 128, BTOT / 128), 256, 0, stream>>>(
        big, ff2w, (size_t)l * CC * 4 * CC, ff2b, (size_t)l * CC,
        h, CC, 4 * CC, flag);
  }
  // LM head -> logits into d_out (element offset +1), in output dtype
  gemm_nt<0, 0, 0, 1><<<dim3((VV + 127) / 128, BTOT / 128), 256, 0, stream>>>(
      h, lmw, 0, nullptr, 0, d_out, VV, CC, flag);
  loss_row_kernel<<<BTOT, 256, 0, stream>>>(d_out, target, rowloss, flag);
  loss_final<<<1, 256, 0, stream>>>(rowloss, d_out, flag);
}